// Round 1
// baseline (434.881 us; speedup 1.0000x reference)
//
#include <hip/hip_runtime.h>
#include <cstdint>
#include <cstddef>

#define GK0 0.7978845608028654f
#define GC1 0.044715f

typedef __attribute__((ext_vector_type(8))) short short8;
typedef __attribute__((ext_vector_type(4))) float floatx4;

__device__ __forceinline__ unsigned short f2bf(float f) {
  union { float f; unsigned int u; } v; v.f = f;
  unsigned int r = v.u + 0x7fffu + ((v.u >> 16) & 1u);   // RNE
  return (unsigned short)(r >> 16);
}

// ---- weights: [co][ci][3][3] f32 -> wt[khw][co][ci] bf16 ----
__global__ void k_wt(const float* __restrict__ w, unsigned short* __restrict__ wt) {
  int t = blockIdx.x * 256 + threadIdx.x;
  if (t >= 128 * 64 * 9) return;
  int co = t / 576; int r = t - co * 576; int ci = r / 9; int khw = r - ci * 9;
  wt[(khw * 128 + co) * 64 + ci] = f2bf(w[t]);
}

// ---- x: [b][ci][128][128] f32 -> xb[b][h][w][ci] bf16 (NHWC) ----
__global__ void k_xt(const float* __restrict__ x, unsigned short* __restrict__ xb) {
  __shared__ float tile[128 * 65];
  int b = blockIdx.y, h = blockIdx.x;
  const float* src = x + ((size_t)b * 64 * 128 + h) * 128;  // x[b][0][h][0], ci stride 128*128
  for (int i = threadIdx.x; i < 64 * 128; i += 256) {
    int ci = i >> 7, w = i & 127;
    tile[w * 65 + ci] = src[(size_t)ci * 16384 + w];        // coalesced along w
  }
  __syncthreads();
  uint32_t* dst = (uint32_t*)(xb + (((size_t)b * 128 + h) * 128) * 64);
  for (int i = threadIdx.x; i < 128 * 32; i += 256) {       // i = w*32 + c2/2
    int w = i >> 5, c2 = (i & 31) << 1;
    uint32_t u0 = f2bf(tile[w * 65 + c2]);
    uint32_t u1 = f2bf(tile[w * 65 + c2 + 1]);
    dst[i] = u0 | (u1 << 16);                                // coalesced
  }
}

// ---- fused conv + bias + gelu + pool ----
// grid (2 wtiles, 63 htiles, 32 b), block 256 (4 waves)
// block tile: M=128 co x N=128 pos (2 h-rows x 64 w), K=576 (9 khw x 64 ci)
__global__ __launch_bounds__(256) void k_conv(
    const unsigned short* __restrict__ xb, const unsigned short* __restrict__ wt,
    const float* __restrict__ bias, float* __restrict__ out) {
  // x tile: 4 rows x 66 w x 64 ci, w-row stride padded 64->72 (2-way-free banks)
  __shared__ unsigned short xs[4 * 66 * 72];
  const int tid = threadIdx.x;
  const int b = blockIdx.z, h0 = blockIdx.y * 2, w0 = blockIdx.x * 64;

  { // stage entire x tile once (covers all 18 K-steps; no barriers in K-loop)
    const size_t base = (((size_t)b * 128 + h0) * 128) * 64;
    for (int t = tid; t < 2112; t += 256) {
      int hi = t / 528; int rem = t - hi * 528; int wi = rem >> 3; int c8 = (rem & 7) << 3;
      int wg = w0 + wi;
      int4 val = make_int4(0, 0, 0, 0);
      if (wg < 128) val = *(const int4*)(xb + base + ((size_t)hi * 128 + wg) * 64 + c8);
      *(int4*)(&xs[(hi * 66 + wi) * 72 + c8]) = val;
    }
  }
  __syncthreads();

  const int lane = tid & 63, wave = tid >> 6;
  const int wm = wave & 1, wn = wave >> 1;      // 2x2 wave grid: co-half, pos-half
  const int m = lane & 15, q = lane >> 4;

  floatx4 acc[4][4];
#pragma unroll
  for (int i = 0; i < 4; i++)
#pragma unroll
    for (int j = 0; j < 4; j++) acc[i][j] = (floatx4){0.f, 0.f, 0.f, 0.f};

  // A (weights): lane holds w[co = wm*64+mt*16+m][ci = cb + q*8 + j]
  const unsigned short* wbase = wt + ((wm * 64 + m) * 64 + q * 8);
  // B (patches): lane holds xs[(wn+kh)][nt*16+m+kw][ci = cb + q*8 + j]
  int bb[4];
#pragma unroll
  for (int nt = 0; nt < 4; nt++) bb[nt] = (wn * 66 + nt * 16 + m) * 72 + q * 8;

  short8 a_cur[4], a_nxt[4];
#pragma unroll
  for (int mt = 0; mt < 4; mt++) a_cur[mt] = *(const short8*)(wbase + mt * 1024);

#pragma unroll
  for (int kk = 0; kk < 18; kk++) {
    const int khw = kk >> 1, cb = (kk & 1) << 5;
    const int kh = khw / 3, kw = khw - kh * 3;
    if (kk < 17) {  // register double-buffer the next A-fragments (hide L2 latency)
      const int khw2 = (kk + 1) >> 1, cb2 = ((kk + 1) & 1) << 5;
      const unsigned short* p = wbase + khw2 * 8192 + cb2;
#pragma unroll
      for (int mt = 0; mt < 4; mt++) a_nxt[mt] = *(const short8*)(p + mt * 1024);
    }
    short8 bf[4];
    const int off = (kh * 66 + kw) * 72 + cb;
#pragma unroll
    for (int nt = 0; nt < 4; nt++) bf[nt] = *(const short8*)(&xs[bb[nt] + off]);
#pragma unroll
    for (int mt = 0; mt < 4; mt++)
#pragma unroll
      for (int nt = 0; nt < 4; nt++)
        acc[mt][nt] = __builtin_amdgcn_mfma_f32_16x16x32_bf16(a_cur[mt], bf[nt], acc[mt][nt], 0, 0, 0);
#pragma unroll
    for (int mt = 0; mt < 4; mt++) a_cur[mt] = a_nxt[mt];
  }

  // epilogue: bias + tanh-GELU + masked pool; D layout: col(n)=lane&15, row(m)=q*4+reg
  const float inv_area = 1.0f / (126.0f * 126.0f);
  float* orow = out + b * 128;
#pragma unroll
  for (int mt = 0; mt < 4; mt++) {
#pragma unroll
    for (int r = 0; r < 4; r++) {
      const int co = wm * 64 + mt * 16 + q * 4 + r;
      const float bv = bias[co];
      float s = 0.0f;
#pragma unroll
      for (int nt = 0; nt < 4; nt++) {
        float y = acc[mt][nt][r] + bv;
        float u = GK0 * (y + GC1 * y * y * y);
        float g = 0.5f * y * (1.0f + tanhf(u));
        if (w0 + nt * 16 + m < 126) s += g;   // mask padded w=126,127
      }
#pragma unroll
      for (int d = 1; d < 16; d <<= 1) s += __shfl_xor(s, d, 64);  // reduce over n-lanes
      if (m == 0) atomicAdd(&orow[co], s * inv_area);
    }
  }
}

extern "C" void kernel_launch(void* const* d_in, const int* in_sizes, int n_in,
                              void* d_out, int out_size, void* d_ws, size_t ws_size,
                              hipStream_t stream) {
  const float* x    = (const float*)d_in[0];
  const float* w    = (const float*)d_in[1];
  const float* bias = (const float*)d_in[2];
  float* out = (float*)d_out;

  unsigned short* xbuf = (unsigned short*)d_ws;                 // 32*128*128*64 bf16 = 64 MiB
  unsigned short* wbuf = xbuf + (size_t)32 * 128 * 128 * 64;    // 73728 bf16
  if (ws_size < (size_t)32 * 128 * 128 * 64 * 2 + 73728 * 2) return;  // fail loudly (zero out)

  hipMemsetAsync(d_out, 0, (size_t)out_size * sizeof(float), stream);
  k_wt<<<288, 256, 0, stream>>>(w, wbuf);
  k_xt<<<dim3(128, 32), 256, 0, stream>>>(x, xbuf);
  k_conv<<<dim3(2, 63, 32), 256, 0, stream>>>(xbuf, wbuf, bias, out);
}

// Round 2
// 397.852 us; speedup vs baseline: 1.0931x; 1.0931x over previous
//
#include <hip/hip_runtime.h>
#include <cstdint>
#include <cstddef>

#define GK0 0.7978845608028654f
#define GC1 0.044715f

typedef __attribute__((ext_vector_type(8))) short short8;
typedef __attribute__((ext_vector_type(4))) float floatx4;

__device__ __forceinline__ unsigned short f2bf(float f) {
  union { float f; unsigned int u; } v; v.f = f;
  unsigned int r = v.u + 0x7fffu + ((v.u >> 16) & 1u);   // RNE
  return (unsigned short)(r >> 16);
}

// ---- weights: [co][ci][3][3] f32 -> wt[khw][co][ci] bf16 ----
__global__ void k_wt(const float* __restrict__ w, unsigned short* __restrict__ wt) {
  int t = blockIdx.x * 256 + threadIdx.x;
  if (t >= 128 * 64 * 9) return;
  int co = t / 576; int r = t - co * 576; int ci = r / 9; int khw = r - ci * 9;
  wt[(khw * 128 + co) * 64 + ci] = f2bf(w[t]);
}

// ---- fused NCHW->bf16 staging + conv + bias + gelu + pool ----
// grid (2 wtiles, 63 htiles, 32 b), block 256 (4 waves)
// block tile: M=128 co x N=128 pos (2 h-rows x 64 w), K=576 (9 khw x 64 ci)
__global__ __launch_bounds__(256, 4) void k_conv(
    const float* __restrict__ x, const unsigned short* __restrict__ wt,
    const float* __restrict__ bias, float* __restrict__ out) {
  // x tile: 4 rows x 66 w x 64 ci (shorts), w-row stride padded 64->72
  __shared__ unsigned short xs[4 * 66 * 72];
  const int tid = threadIdx.x;
  const int b = blockIdx.z, h0 = blockIdx.y * 2, w0 = blockIdx.x * 64;

  { // stage directly from NCHW fp32: thread t -> (ci = t>>2, hi = t&3), streams 66 w
    const int ci = tid >> 2, hi = tid & 3;
    const float* src = x + ((size_t)(b * 64 + ci) * 128 + (h0 + hi)) * 128 + w0;
    unsigned short* dst = xs + (hi * 66) * 72 + ci;          // + wi*72
#pragma unroll 4
    for (int v = 0; v < 16; v++) {
      float4 f = ((const float4*)src)[v];                    // 16B aligned (w0 % 64 == 0)
      dst[(4 * v + 0) * 72] = f2bf(f.x);
      dst[(4 * v + 1) * 72] = f2bf(f.y);
      dst[(4 * v + 2) * 72] = f2bf(f.z);
      dst[(4 * v + 3) * 72] = f2bf(f.w);
    }
    const bool ok = (w0 == 0);                               // w0+64/65 in-range only for w0=0
    dst[64 * 72] = ok ? f2bf(src[64]) : (unsigned short)0;
    dst[65 * 72] = ok ? f2bf(src[65]) : (unsigned short)0;
  }
  __syncthreads();

  const int lane = tid & 63, wave = tid >> 6;
  const int wm = wave & 1, wn = wave >> 1;      // 2x2 wave grid: co-half, pos-half
  const int m = lane & 15, q = lane >> 4;

  floatx4 acc[4][4];
#pragma unroll
  for (int i = 0; i < 4; i++)
#pragma unroll
    for (int j = 0; j < 4; j++) acc[i][j] = (floatx4){0.f, 0.f, 0.f, 0.f};

  // A (weights): lane holds w[co = wm*64+mt*16+m][ci = cb + q*8 + j]
  const unsigned short* wbase = wt + ((wm * 64 + m) * 64 + q * 8);
  // B (patches): lane holds xs[(wn+kh)][nt*16+m+kw][ci = cb + q*8 + j]
  int bb[4];
#pragma unroll
  for (int nt = 0; nt < 4; nt++) bb[nt] = (wn * 66 + nt * 16 + m) * 72 + q * 8;

  short8 a_cur[4], a_nxt[4];
#pragma unroll
  for (int mt = 0; mt < 4; mt++) a_cur[mt] = *(const short8*)(wbase + mt * 1024);

#pragma unroll
  for (int kk = 0; kk < 18; kk++) {
    const int khw = kk >> 1, cb = (kk & 1) << 5;
    const int kh = khw / 3, kw = khw - kh * 3;
    if (kk < 17) {  // register double-buffer next A-fragments (hide L2 latency)
      const int khw2 = (kk + 1) >> 1, cb2 = ((kk + 1) & 1) << 5;
      const unsigned short* p = wbase + khw2 * 8192 + cb2;
#pragma unroll
      for (int mt = 0; mt < 4; mt++) a_nxt[mt] = *(const short8*)(p + mt * 1024);
    }
    short8 bf[4];
    const int off = (kh * 66 + kw) * 72 + cb;
#pragma unroll
    for (int nt = 0; nt < 4; nt++) bf[nt] = *(const short8*)(&xs[bb[nt] + off]);
#pragma unroll
    for (int mt = 0; mt < 4; mt++)
#pragma unroll
      for (int nt = 0; nt < 4; nt++)
        acc[mt][nt] = __builtin_amdgcn_mfma_f32_16x16x32_bf16(a_cur[mt], bf[nt], acc[mt][nt], 0, 0, 0);
#pragma unroll
    for (int mt = 0; mt < 4; mt++) a_cur[mt] = a_nxt[mt];
  }

  // epilogue: bias + fast tanh-GELU (y*sigmoid(2u)) + masked pool
  // D layout: col(n)=lane&15, row(m)=q*4+reg
  const float inv_area = 1.0f / (126.0f * 126.0f);
  float* orow = out + b * 128;
#pragma unroll
  for (int mt = 0; mt < 4; mt++) {
#pragma unroll
    for (int r = 0; r < 4; r++) {
      const int co = wm * 64 + mt * 16 + q * 4 + r;
      const float bv = bias[co];
      float s = 0.0f;
#pragma unroll
      for (int nt = 0; nt < 4; nt++) {
        float y = acc[mt][nt][r] + bv;
        float u = GK0 * (y + GC1 * y * y * y);
        float e = __expf(-2.0f * u);                          // v_exp_f32 path
        float g = y * __builtin_amdgcn_rcpf(1.0f + e);        // == 0.5y(1+tanh(u))
        if (w0 + nt * 16 + m < 126) s += g;                   // mask padded w=126,127
      }
#pragma unroll
      for (int d = 1; d < 16; d <<= 1) s += __shfl_xor(s, d, 64);  // reduce over n-lanes
      if (m == 0) atomicAdd(&orow[co], s * inv_area);
    }
  }
}

extern "C" void kernel_launch(void* const* d_in, const int* in_sizes, int n_in,
                              void* d_out, int out_size, void* d_ws, size_t ws_size,
                              hipStream_t stream) {
  const float* x    = (const float*)d_in[0];
  const float* w    = (const float*)d_in[1];
  const float* bias = (const float*)d_in[2];
  float* out = (float*)d_out;

  unsigned short* wbuf = (unsigned short*)d_ws;   // 9*128*64 bf16 = 144 KiB
  if (ws_size < (size_t)9 * 128 * 64 * 2) return;

  hipMemsetAsync(d_out, 0, (size_t)out_size * sizeof(float), stream);
  k_wt<<<288, 256, 0, stream>>>(w, wbuf);
  k_conv<<<dim3(2, 63, 32), 256, 0, stream>>>(x, wbuf, bias, out);
}